// Round 1
// baseline (496.657 us; speedup 1.0000x reference)
//
#include <hip/hip_runtime.h>

#define DIM 768
#define D_STATE 16
#define D_CONV 4
#define DT_RANK 32
#define D_INNER 1536
#define BATCH 2
#define SEQ 1024
#define BL (BATCH * SEQ)   // 2048
#define E2 (2 * D_INNER)   // 3072

__device__ __forceinline__ float silu_f(float v) {
    return v / (1.0f + __expf(-v));
}
__device__ __forceinline__ float softplus_f(float v) {
    return fmaxf(v, 0.0f) + log1pf(__expf(-fabsf(v)));
}

// ---------------------------------------------------------------------------
// Generic NT GEMM: C[M,N] = A[M,K] (row-major, lda) * B[N,K]^T (row-major, ldb)
// EPI 0: none; EPI 1: softplus(acc + 2*X[col]); EPI 2: acc + X[row*ldx+col]
// 256 threads, 64x64 tile, BK=16, 4x4 per-thread microtile.
// Requires M,N %64==0, K%16==0, rows 16B-aligned.
// ---------------------------------------------------------------------------
template <int EPI>
__global__ __launch_bounds__(256) void gemm_nt(
    const float* __restrict__ A, int lda,
    const float* __restrict__ B, int ldb,
    float* __restrict__ C, int ldc,
    const float* __restrict__ X, int ldx,
    int M, int N, int K)
{
    __shared__ float As[16][68];
    __shared__ float Bs[16][68];
    const int bm = blockIdx.y * 64;
    const int bn = blockIdx.x * 64;
    const int tid = threadIdx.x;
    const int lm = tid >> 2;          // 0..63 : row within tile for loads
    const int lk = (tid & 3) << 2;    // 0,4,8,12 : k offset for loads
    const int tn = (tid & 15) << 2;   // col group
    const int tm = (tid >> 4) << 2;   // row group

    float acc[4][4] = {};
    const float* Aptr = A + (size_t)(bm + lm) * lda + lk;
    const float* Bptr = B + (size_t)(bn + lm) * ldb + lk;

    for (int k0 = 0; k0 < K; k0 += 16) {
        const float4 av = *reinterpret_cast<const float4*>(Aptr + k0);
        const float4 bv = *reinterpret_cast<const float4*>(Bptr + k0);
        As[lk + 0][lm] = av.x; As[lk + 1][lm] = av.y;
        As[lk + 2][lm] = av.z; As[lk + 3][lm] = av.w;
        Bs[lk + 0][lm] = bv.x; Bs[lk + 1][lm] = bv.y;
        Bs[lk + 2][lm] = bv.z; Bs[lk + 3][lm] = bv.w;
        __syncthreads();
#pragma unroll
        for (int kk = 0; kk < 16; ++kk) {
            const float4 a = *reinterpret_cast<const float4*>(&As[kk][tm]);
            const float4 b = *reinterpret_cast<const float4*>(&Bs[kk][tn]);
            acc[0][0] += a.x * b.x; acc[0][1] += a.x * b.y; acc[0][2] += a.x * b.z; acc[0][3] += a.x * b.w;
            acc[1][0] += a.y * b.x; acc[1][1] += a.y * b.y; acc[1][2] += a.y * b.z; acc[1][3] += a.y * b.w;
            acc[2][0] += a.z * b.x; acc[2][1] += a.z * b.y; acc[2][2] += a.z * b.z; acc[2][3] += a.z * b.w;
            acc[3][0] += a.w * b.x; acc[3][1] += a.w * b.y; acc[3][2] += a.w * b.z; acc[3][3] += a.w * b.w;
        }
        __syncthreads();
    }

#pragma unroll
    for (int i = 0; i < 4; ++i) {
        const int row = bm + tm + i;
#pragma unroll
        for (int j = 0; j < 4; ++j) {
            const int col = bn + tn + j;
            float v = acc[i][j];
            if (EPI == 1) v = softplus_f(v + 2.0f * X[col]);
            if (EPI == 2) v += X[(size_t)row * ldx + col];
            C[(size_t)row * ldc + col] = v;
        }
    }
}

// ---------------------------------------------------------------------------
// Depthwise causal conv (k=4) + bias + SiLU.  In: xc half of xz (stride E2).
// Out: xcs (stride D_INNER).
// ---------------------------------------------------------------------------
__global__ __launch_bounds__(256) void conv_silu_kernel(
    const float* __restrict__ xz, const float* __restrict__ Wc,
    const float* __restrict__ bc, float* __restrict__ xcs)
{
    const int idx = blockIdx.x * 256 + threadIdx.x;
    if (idx >= BL * D_INNER) return;
    const int d = idx % D_INNER;
    const int bl = idx / D_INNER;
    const int l = bl % SEQ;
    const float w0 = Wc[d * 4 + 0], w1 = Wc[d * 4 + 1];
    const float w2 = Wc[d * 4 + 2], w3 = Wc[d * 4 + 3];
    float acc = bc[d] + w3 * xz[(size_t)bl * E2 + d];
    if (l >= 1) acc += w2 * xz[(size_t)(bl - 1) * E2 + d];
    if (l >= 2) acc += w1 * xz[(size_t)(bl - 2) * E2 + d];
    if (l >= 3) acc += w0 * xz[(size_t)(bl - 3) * E2 + d];
    xcs[idx] = silu_f(acc);
}

// ---------------------------------------------------------------------------
// x_dbl = xcs @ W_x^T   (M=2048, N=64, K=1536).  8 rows per block; 256 thr:
// j = tid&63 output col, rq = tid>>6 k-quarter; LDS reduce across quarters.
// ---------------------------------------------------------------------------
__global__ __launch_bounds__(256) void xdbl_kernel(
    const float* __restrict__ xcs, const float* __restrict__ W_x,
    float* __restrict__ xdbl)
{
    __shared__ float xr[8][1536];
    const int r0 = blockIdx.x * 8;
    const int tid = threadIdx.x;

    for (int v = tid; v < 8 * 1536 / 4; v += 256) {
        const int rr = v / 384;
        const int kk = (v % 384) * 4;
        *reinterpret_cast<float4*>(&xr[rr][kk]) =
            *reinterpret_cast<const float4*>(&xcs[(size_t)(r0 + rr) * D_INNER + kk]);
    }
    __syncthreads();

    const int j = tid & 63;
    const int rq = tid >> 6;          // 0..3
    const float* w = W_x + (size_t)j * D_INNER + rq * 384;
    float acc[8] = {};
    for (int k = 0; k < 384; k += 4) {
        const float4 wv = *reinterpret_cast<const float4*>(w + k);
#pragma unroll
        for (int r = 0; r < 8; ++r) {
            const float4 xv = *reinterpret_cast<const float4*>(&xr[r][rq * 384 + k]);
            acc[r] += wv.x * xv.x + wv.y * xv.y + wv.z * xv.z + wv.w * xv.w;
        }
    }
    __syncthreads();
    float* red = &xr[0][0];           // reuse LDS: 64*4*8 = 2048 floats
#pragma unroll
    for (int r = 0; r < 8; ++r) red[j * 32 + rq * 8 + r] = acc[r];
    __syncthreads();
    if (rq == 0) {
#pragma unroll
        for (int r = 0; r < 8; ++r) {
            const float s = red[j * 32 + r] + red[j * 32 + 8 + r] +
                            red[j * 32 + 16 + r] + red[j * 32 + 24 + r];
            xdbl[(size_t)(r0 + r) * 64 + j] = s;
        }
    }
}

// ---------------------------------------------------------------------------
// Selective scan.  Block = 256 thr = 16 channels x 16 states; grid (96, 2).
// Chunked LDS staging of dt/xc/B/C (64 steps), shfl_xor reduction over states.
// ---------------------------------------------------------------------------
__global__ __launch_bounds__(256) void scan_kernel(
    const float* __restrict__ dtg, const float* __restrict__ xcs,
    const float* __restrict__ xdbl, const float* __restrict__ A_log,
    const float* __restrict__ Dp, float* __restrict__ y)
{
    __shared__ float dt_s[64][16];
    __shared__ float xc_s[64][16];
    __shared__ float B_s[64][16];
    __shared__ float C_s[64][16];
    const int tid = threadIdx.x;
    const int s = tid & 15;
    const int dl = tid >> 4;
    const int d0 = blockIdx.x * 16;
    const int b = blockIdx.y;
    const int d = d0 + dl;
    const int row0 = b * SEQ;
    const float a = -__expf(A_log[d * D_STATE + s]);
    const float Dd = Dp[d];
    float h = 0.0f;

    for (int l0 = 0; l0 < SEQ; l0 += 64) {
        __syncthreads();
#pragma unroll
        for (int p = 0; p < 4; ++p) {
            const int i = p * 16 + dl;      // staging: dl is the step index, s the lane col
            const size_t r = (size_t)(row0 + l0 + i);
            dt_s[i][s] = dtg[r * D_INNER + d0 + s];
            xc_s[i][s] = xcs[r * D_INNER + d0 + s];
            B_s[i][s]  = xdbl[r * 64 + 32 + s];
            C_s[i][s]  = xdbl[r * 64 + 48 + s];
        }
        __syncthreads();
#pragma unroll 4
        for (int i = 0; i < 64; ++i) {
            const float dtv = dt_s[i][dl];
            const float xcv = xc_s[i][dl];
            const float Bv = B_s[i][s];
            const float Cv = C_s[i][s];
            h = __expf(dtv * a) * h + dtv * Bv * xcv;
            float v = h * Cv;
            v += __shfl_xor(v, 1);
            v += __shfl_xor(v, 2);
            v += __shfl_xor(v, 4);
            v += __shfl_xor(v, 8);
            if (s == 0) y[(size_t)(row0 + l0 + i) * D_INNER + d] = v + xcv * Dd;
        }
    }
}

// ---------------------------------------------------------------------------
// ym = y * silu(z) written into xc half of xz (in place, stride E2).
// ---------------------------------------------------------------------------
__global__ __launch_bounds__(256) void ymul_kernel(
    const float* __restrict__ y, float* __restrict__ xz)
{
    const int idx = blockIdx.x * 256 + threadIdx.x;
    if (idx >= BL * D_INNER) return;
    const int row = idx / D_INNER;
    const int c = idx % D_INNER;
    const float z = xz[(size_t)row * E2 + D_INNER + c];
    xz[(size_t)row * E2 + c] = y[idx] * silu_f(z);
}

extern "C" void kernel_launch(void* const* d_in, const int* in_sizes, int n_in,
                              void* d_out, int out_size, void* d_ws, size_t ws_size,
                              hipStream_t stream) {
    const float* x      = (const float*)d_in[0];
    const float* W_in   = (const float*)d_in[1];
    const float* W_conv = (const float*)d_in[2];
    const float* b_conv = (const float*)d_in[3];
    const float* W_x    = (const float*)d_in[4];
    const float* W_dt   = (const float*)d_in[5];
    const float* b_dt   = (const float*)d_in[6];
    const float* A_log  = (const float*)d_in[7];
    const float* Dp     = (const float*)d_in[8];
    const float* W_out  = (const float*)d_in[9];
    float* out = (float*)d_out;

    float* ws   = (float*)d_ws;
    float* xz   = ws;                               // BL * 3072
    float* xcs  = xz + (size_t)BL * E2;             // BL * 1536
    float* xdbl = xcs + (size_t)BL * D_INNER;       // BL * 64
    float* dtg  = xdbl + (size_t)BL * 64;           // BL * 1536
    float* yb   = dtg + (size_t)BL * D_INNER;       // BL * 1536

    // 1. xz = x @ W_in^T
    gemm_nt<0><<<dim3(E2 / 64, BL / 64), 256, 0, stream>>>(
        x, DIM, W_in, DIM, xz, E2, nullptr, 0, BL, E2, DIM);
    // 2. depthwise causal conv + bias + silu
    conv_silu_kernel<<<(BL * D_INNER) / 256, 256, 0, stream>>>(xz, W_conv, b_conv, xcs);
    // 3. x_dbl = xcs @ W_x^T
    xdbl_kernel<<<BL / 8, 256, 0, stream>>>(xcs, W_x, xdbl);
    // 4. dt = softplus(dt_lr @ W_dt^T + 2*b_dt)
    gemm_nt<1><<<dim3(D_INNER / 64, BL / 64), 256, 0, stream>>>(
        xdbl, 64, W_dt, DT_RANK, dtg, D_INNER, b_dt, 0, BL, D_INNER, DT_RANK);
    // 5. selective scan -> y
    scan_kernel<<<dim3(D_INNER / 16, BATCH), 256, 0, stream>>>(
        dtg, xcs, xdbl, A_log, Dp, yb);
    // 6. ym = y * silu(z) into xc half of xz
    ymul_kernel<<<(BL * D_INNER) / 256, 256, 0, stream>>>(yb, xz);
    // 7. out = ym @ W_out^T + x
    gemm_nt<2><<<dim3(DIM / 64, BL / 64), 256, 0, stream>>>(
        xz, E2, W_out, D_INNER, out, DIM, x, DIM, BL, DIM, D_INNER);
}

// Round 2
// 365.784 us; speedup vs baseline: 1.3578x; 1.3578x over previous
//
#include <hip/hip_runtime.h>

#define DIM 768
#define D_STATE 16
#define D_CONV 4
#define DT_RANK 32
#define D_INNER 1536
#define BATCH 2
#define SEQ 1024
#define BL (BATCH * SEQ)   // 2048
#define E2 (2 * D_INNER)   // 3072
#define NCHUNK 16
#define TCH (SEQ / NCHUNK) // 64

__device__ __forceinline__ float silu_f(float v) {
    return v / (1.0f + __expf(-v));
}
__device__ __forceinline__ float softplus_f(float v) {
    return fmaxf(v, 0.0f) + log1pf(__expf(-fabsf(v)));
}

// ---------------------------------------------------------------------------
// Generic NT GEMM: C[M,N] = A[M,K] (row-major, lda) * B[N,K]^T (row-major, ldb)
// EPI 0: none; EPI 1: softplus(acc + 2*X[col]); EPI 2: acc + X[row*ldx+col]
// 256 threads, 64x64 tile, BK=16, 4x4 per-thread microtile.
// ---------------------------------------------------------------------------
template <int EPI>
__global__ __launch_bounds__(256) void gemm_nt(
    const float* __restrict__ A, int lda,
    const float* __restrict__ B, int ldb,
    float* __restrict__ C, int ldc,
    const float* __restrict__ X, int ldx,
    int M, int N, int K)
{
    __shared__ float As[16][68];
    __shared__ float Bs[16][68];
    const int bm = blockIdx.y * 64;
    const int bn = blockIdx.x * 64;
    const int tid = threadIdx.x;
    const int lm = tid >> 2;          // 0..63 : row within tile for loads
    const int lk = (tid & 3) << 2;    // 0,4,8,12 : k offset for loads
    const int tn = (tid & 15) << 2;   // col group
    const int tm = (tid >> 4) << 2;   // row group

    float acc[4][4] = {};
    const float* Aptr = A + (size_t)(bm + lm) * lda + lk;
    const float* Bptr = B + (size_t)(bn + lm) * ldb + lk;

    for (int k0 = 0; k0 < K; k0 += 16) {
        const float4 av = *reinterpret_cast<const float4*>(Aptr + k0);
        const float4 bv = *reinterpret_cast<const float4*>(Bptr + k0);
        As[lk + 0][lm] = av.x; As[lk + 1][lm] = av.y;
        As[lk + 2][lm] = av.z; As[lk + 3][lm] = av.w;
        Bs[lk + 0][lm] = bv.x; Bs[lk + 1][lm] = bv.y;
        Bs[lk + 2][lm] = bv.z; Bs[lk + 3][lm] = bv.w;
        __syncthreads();
#pragma unroll
        for (int kk = 0; kk < 16; ++kk) {
            const float4 a = *reinterpret_cast<const float4*>(&As[kk][tm]);
            const float4 b = *reinterpret_cast<const float4*>(&Bs[kk][tn]);
            acc[0][0] += a.x * b.x; acc[0][1] += a.x * b.y; acc[0][2] += a.x * b.z; acc[0][3] += a.x * b.w;
            acc[1][0] += a.y * b.x; acc[1][1] += a.y * b.y; acc[1][2] += a.y * b.z; acc[1][3] += a.y * b.w;
            acc[2][0] += a.z * b.x; acc[2][1] += a.z * b.y; acc[2][2] += a.z * b.z; acc[2][3] += a.z * b.w;
            acc[3][0] += a.w * b.x; acc[3][1] += a.w * b.y; acc[3][2] += a.w * b.z; acc[3][3] += a.w * b.w;
        }
        __syncthreads();
    }

#pragma unroll
    for (int i = 0; i < 4; ++i) {
        const int row = bm + tm + i;
#pragma unroll
        for (int j = 0; j < 4; ++j) {
            const int col = bn + tn + j;
            float v = acc[i][j];
            if (EPI == 1) v = softplus_f(v + 2.0f * X[col]);
            if (EPI == 2) v += X[(size_t)row * ldx + col];
            C[(size_t)row * ldc + col] = v;
        }
    }
}

// ---------------------------------------------------------------------------
// Depthwise causal conv (k=4) + bias + SiLU.
// ---------------------------------------------------------------------------
__global__ __launch_bounds__(256) void conv_silu_kernel(
    const float* __restrict__ xz, const float* __restrict__ Wc,
    const float* __restrict__ bc, float* __restrict__ xcs)
{
    const int idx = blockIdx.x * 256 + threadIdx.x;
    if (idx >= BL * D_INNER) return;
    const int d = idx % D_INNER;
    const int bl = idx / D_INNER;
    const int l = bl % SEQ;
    const float w0 = Wc[d * 4 + 0], w1 = Wc[d * 4 + 1];
    const float w2 = Wc[d * 4 + 2], w3 = Wc[d * 4 + 3];
    float acc = bc[d] + w3 * xz[(size_t)bl * E2 + d];
    if (l >= 1) acc += w2 * xz[(size_t)(bl - 1) * E2 + d];
    if (l >= 2) acc += w1 * xz[(size_t)(bl - 2) * E2 + d];
    if (l >= 3) acc += w0 * xz[(size_t)(bl - 3) * E2 + d];
    xcs[idx] = silu_f(acc);
}

// ---------------------------------------------------------------------------
// x_dbl = xcs @ W_x^T   (M=2048, N=64, K=1536).
// ---------------------------------------------------------------------------
__global__ __launch_bounds__(256) void xdbl_kernel(
    const float* __restrict__ xcs, const float* __restrict__ W_x,
    float* __restrict__ xdbl)
{
    __shared__ float xr[8][1536];
    const int r0 = blockIdx.x * 8;
    const int tid = threadIdx.x;

    for (int v = tid; v < 8 * 1536 / 4; v += 256) {
        const int rr = v / 384;
        const int kk = (v % 384) * 4;
        *reinterpret_cast<float4*>(&xr[rr][kk]) =
            *reinterpret_cast<const float4*>(&xcs[(size_t)(r0 + rr) * D_INNER + kk]);
    }
    __syncthreads();

    const int j = tid & 63;
    const int rq = tid >> 6;          // 0..3
    const float* w = W_x + (size_t)j * D_INNER + rq * 384;
    float acc[8] = {};
    for (int k = 0; k < 384; k += 4) {
        const float4 wv = *reinterpret_cast<const float4*>(w + k);
#pragma unroll
        for (int r = 0; r < 8; ++r) {
            const float4 xv = *reinterpret_cast<const float4*>(&xr[r][rq * 384 + k]);
            acc[r] += wv.x * xv.x + wv.y * xv.y + wv.z * xv.z + wv.w * xv.w;
        }
    }
    __syncthreads();
    float* red = &xr[0][0];
#pragma unroll
    for (int r = 0; r < 8; ++r) red[j * 32 + rq * 8 + r] = acc[r];
    __syncthreads();
    if (rq == 0) {
#pragma unroll
        for (int r = 0; r < 8; ++r) {
            const float s = red[j * 32 + r] + red[j * 32 + 8 + r] +
                            red[j * 32 + 16 + r] + red[j * 32 + 24 + r];
            xdbl[(size_t)(r0 + r) * 64 + j] = s;
        }
    }
}

// ---------------------------------------------------------------------------
// Chunked selective scan.  h_t = e_t h_{t-1} + u_t is associative; split
// L=1024 into 16 chunks of 64.  Pass1: per-chunk (E=prod e, Hloc).  Pass2:
// tiny sequential combine over 16 chunks.  Pass3: rescan chunk from Hinit,
// emit y.  16x more blocks than the monolithic scan -> full occupancy.
// Block = 256 thr = 16 channels x 16 states; grid (96, 16, 2).
// ---------------------------------------------------------------------------
__global__ __launch_bounds__(256) void scan_pass1(
    const float* __restrict__ dtg, const float* __restrict__ xcs,
    const float* __restrict__ xdbl, const float* __restrict__ A_log,
    float* __restrict__ Ec, float* __restrict__ Hc)
{
    __shared__ float dt_s[TCH][16];
    __shared__ float xc_s[TCH][16];
    __shared__ float B_s[TCH][16];
    const int tid = threadIdx.x;
    const int s = tid & 15;
    const int dl = tid >> 4;
    const int d0 = blockIdx.x * 16;
    const int c = blockIdx.y;
    const int b = blockIdx.z;
    const int d = d0 + dl;
    const int r0 = b * SEQ + c * TCH;
    const float a = -__expf(A_log[d * D_STATE + s]);

#pragma unroll
    for (int p = 0; p < 4; ++p) {
        const int i = p * 16 + dl;
        const size_t r = (size_t)(r0 + i);
        dt_s[i][s] = dtg[r * D_INNER + d0 + s];
        xc_s[i][s] = xcs[r * D_INNER + d0 + s];
        B_s[i][s]  = xdbl[r * 64 + 32 + s];
    }
    __syncthreads();

    float E = 1.0f, h = 0.0f;
#pragma unroll 8
    for (int i = 0; i < TCH; ++i) {
        const float dtv = dt_s[i][dl];
        const float e = __expf(dtv * a);
        E *= e;
        h = e * h + dtv * B_s[i][s] * xc_s[i][dl];
    }
    const size_t o = ((size_t)(b * NCHUNK + c) * D_INNER + d) * 16 + s;
    Ec[o] = E;
    Hc[o] = h;
}

__global__ __launch_bounds__(256) void scan_pass2(
    const float* __restrict__ Ec, const float* __restrict__ Hc,
    float* __restrict__ Hinit)
{
    const int idx = blockIdx.x * 256 + threadIdx.x;  // b*D_INNER*16 + d*16 + s
    if (idx >= BATCH * D_INNER * 16) return;
    const int b = idx / (D_INNER * 16);
    const int ds = idx % (D_INNER * 16);
    float h = 0.0f;
#pragma unroll
    for (int c = 0; c < NCHUNK; ++c) {
        const size_t o = (size_t)(b * NCHUNK + c) * (D_INNER * 16) + ds;
        Hinit[o] = h;
        h = Ec[o] * h + Hc[o];
    }
}

__global__ __launch_bounds__(256) void scan_pass3(
    const float* __restrict__ dtg, const float* __restrict__ xcs,
    const float* __restrict__ xdbl, const float* __restrict__ A_log,
    const float* __restrict__ Dp, const float* __restrict__ Hinit,
    float* __restrict__ y)   // y may alias dtg: block reads/writes same region
{
    __shared__ float dt_s[TCH][16];
    __shared__ float xc_s[TCH][16];
    __shared__ float B_s[TCH][16];
    __shared__ float C_s[TCH][16];
    const int tid = threadIdx.x;
    const int s = tid & 15;
    const int dl = tid >> 4;
    const int d0 = blockIdx.x * 16;
    const int c = blockIdx.y;
    const int b = blockIdx.z;
    const int d = d0 + dl;
    const int r0 = b * SEQ + c * TCH;
    const float a = -__expf(A_log[d * D_STATE + s]);
    const float Dd = Dp[d];

#pragma unroll
    for (int p = 0; p < 4; ++p) {
        const int i = p * 16 + dl;
        const size_t r = (size_t)(r0 + i);
        dt_s[i][s] = dtg[r * D_INNER + d0 + s];
        xc_s[i][s] = xcs[r * D_INNER + d0 + s];
        B_s[i][s]  = xdbl[r * 64 + 32 + s];
        C_s[i][s]  = xdbl[r * 64 + 48 + s];
    }
    __syncthreads();

    float h = Hinit[((size_t)(b * NCHUNK + c) * D_INNER + d) * 16 + s];
#pragma unroll 4
    for (int i = 0; i < TCH; ++i) {
        const float dtv = dt_s[i][dl];
        const float xcv = xc_s[i][dl];
        const float e = __expf(dtv * a);
        h = e * h + dtv * B_s[i][s] * xcv;
        float v = h * C_s[i][s];
        v += __shfl_xor(v, 1);
        v += __shfl_xor(v, 2);
        v += __shfl_xor(v, 4);
        v += __shfl_xor(v, 8);
        if (s == 0) y[(size_t)(r0 + i) * D_INNER + d] = v + xcv * Dd;
    }
}

// ---------------------------------------------------------------------------
// ym = y * silu(z) written into xc half of xz (in place, stride E2).
// ---------------------------------------------------------------------------
__global__ __launch_bounds__(256) void ymul_kernel(
    const float* __restrict__ y, float* __restrict__ xz)
{
    const int idx = blockIdx.x * 256 + threadIdx.x;
    if (idx >= BL * D_INNER) return;
    const int row = idx / D_INNER;
    const int c = idx % D_INNER;
    const float z = xz[(size_t)row * E2 + D_INNER + c];
    xz[(size_t)row * E2 + c] = y[idx] * silu_f(z);
}

extern "C" void kernel_launch(void* const* d_in, const int* in_sizes, int n_in,
                              void* d_out, int out_size, void* d_ws, size_t ws_size,
                              hipStream_t stream) {
    const float* x      = (const float*)d_in[0];
    const float* W_in   = (const float*)d_in[1];
    const float* W_conv = (const float*)d_in[2];
    const float* b_conv = (const float*)d_in[3];
    const float* W_x    = (const float*)d_in[4];
    const float* W_dt   = (const float*)d_in[5];
    const float* b_dt   = (const float*)d_in[6];
    const float* A_log  = (const float*)d_in[7];
    const float* Dp     = (const float*)d_in[8];
    const float* W_out  = (const float*)d_in[9];
    float* out = (float*)d_out;

    float* ws    = (float*)d_ws;
    float* xz    = ws;                               // BL * 3072
    float* xcs   = xz + (size_t)BL * E2;             // BL * 1536
    float* xdbl  = xcs + (size_t)BL * D_INNER;       // BL * 64
    float* dtg   = xdbl + (size_t)BL * 64;           // BL * 1536 (also y)
    float* Ec    = dtg + (size_t)BL * D_INNER;       // 2*16*1536*16
    float* Hc    = Ec + (size_t)BATCH * NCHUNK * D_INNER * 16;
    float* Hinit = Hc + (size_t)BATCH * NCHUNK * D_INNER * 16;
    float* yb    = dtg;                              // pass3 writes y over dtg

    // 1. xz = x @ W_in^T
    gemm_nt<0><<<dim3(E2 / 64, BL / 64), 256, 0, stream>>>(
        x, DIM, W_in, DIM, xz, E2, nullptr, 0, BL, E2, DIM);
    // 2. depthwise causal conv + bias + silu
    conv_silu_kernel<<<(BL * D_INNER) / 256, 256, 0, stream>>>(xz, W_conv, b_conv, xcs);
    // 3. x_dbl = xcs @ W_x^T
    xdbl_kernel<<<BL / 8, 256, 0, stream>>>(xcs, W_x, xdbl);
    // 4. dt = softplus(dt_lr @ W_dt^T + 2*b_dt)
    gemm_nt<1><<<dim3(D_INNER / 64, BL / 64), 256, 0, stream>>>(
        xdbl, 64, W_dt, DT_RANK, dtg, D_INNER, b_dt, 0, BL, D_INNER, DT_RANK);
    // 5. chunked selective scan -> y (over dtg)
    scan_pass1<<<dim3(D_INNER / 16, NCHUNK, BATCH), 256, 0, stream>>>(
        dtg, xcs, xdbl, A_log, Ec, Hc);
    scan_pass2<<<(BATCH * D_INNER * 16) / 256, 256, 0, stream>>>(Ec, Hc, Hinit);
    scan_pass3<<<dim3(D_INNER / 16, NCHUNK, BATCH), 256, 0, stream>>>(
        dtg, xcs, xdbl, A_log, Dp, Hinit, yb);
    // 6. ym = y * silu(z) into xc half of xz
    ymul_kernel<<<(BL * D_INNER) / 256, 256, 0, stream>>>(yb, xz);
    // 7. out = ym @ W_out^T + x
    gemm_nt<2><<<dim3(DIM / 64, BL / 64), 256, 0, stream>>>(
        xz, E2, W_out, D_INNER, out, DIM, x, DIM, BL, DIM, D_INNER);
}

// Round 3
// 204.916 us; speedup vs baseline: 2.4237x; 1.7850x over previous
//
#include <hip/hip_runtime.h>
#include <stdint.h>

#define DIM 768
#define D_STATE 16
#define D_CONV 4
#define DT_RANK 32
#define D_INNER 1536
#define BATCH 2
#define SEQ 1024
#define BL (BATCH * SEQ)   // 2048
#define E2 (2 * D_INNER)   // 3072
#define NCHUNK 16
#define TCH (SEQ / NCHUNK) // 64

typedef __attribute__((ext_vector_type(8))) __bf16 bf16x8;
typedef __attribute__((ext_vector_type(4))) float f32x4;
typedef __attribute__((ext_vector_type(8))) unsigned short u16x8;

__device__ __forceinline__ float silu_f(float v) {
    return v / (1.0f + __expf(-v));
}
__device__ __forceinline__ float softplus_f(float v) {
    return fmaxf(v, 0.0f) + log1pf(__expf(-fabsf(v)));
}
__device__ __forceinline__ unsigned short f2bf(float f) {
    uint32_t u = __float_as_uint(f);
    u += 0x7FFFu + ((u >> 16) & 1u);          // round-to-nearest-even
    return (unsigned short)(u >> 16);
}
// global -> LDS direct copy, 16B per lane. LDS dest: wave-uniform base + lane*16.
__device__ __forceinline__ void gload_lds16(const void* g, void* l) {
    __builtin_amdgcn_global_load_lds(
        (const __attribute__((address_space(1))) unsigned int*)(uintptr_t)g,
        (__attribute__((address_space(3))) unsigned int*)(uint32_t)(uintptr_t)l,
        16, 0, 0);
}

// ---------------------------------------------------------------------------
// f32 -> bf16 conversion, 8 elems/thread.
// ---------------------------------------------------------------------------
__global__ __launch_bounds__(256) void cvt_bf16_kernel(
    const float* __restrict__ src, unsigned short* __restrict__ dst, int n8)
{
    const int i = blockIdx.x * 256 + threadIdx.x;
    if (i >= n8) return;
    const f32x4 a = ((const f32x4*)src)[2 * i];
    const f32x4 b = ((const f32x4*)src)[2 * i + 1];
    u16x8 o;
#pragma unroll
    for (int j = 0; j < 4; ++j) { o[j] = f2bf(a[j]); o[4 + j] = f2bf(b[j]); }
    ((u16x8*)dst)[i] = o;
}

// ---------------------------------------------------------------------------
// bf16 MFMA GEMM: C[M,N] fp32 = A[M,K]bf16 * B[N,K]^T bf16 (+X residual).
// 128x128 tile, BK=32, 256 thr = 4 waves (2x2), 16x16x32 MFMA, 4x4 frags/wave.
// global_load_lds w=16 staging; grid (N/128, M/128).
// EPI 0: none.  EPI 2: += X[row*ldx+col].
// ---------------------------------------------------------------------------
template <int EPI>
__global__ __launch_bounds__(256) void gemm_bf16(
    const unsigned short* __restrict__ A, const unsigned short* __restrict__ B,
    float* __restrict__ C, int ldc,
    const float* __restrict__ X, int ldx, int K)
{
    __shared__ __align__(16) unsigned short As[128 * 32];
    __shared__ __align__(16) unsigned short Bs[128 * 32];
    const int tid = threadIdx.x;
    const int wid = tid >> 6;
    const int lane = tid & 63;
    const int wr = wid >> 1, wc = wid & 1;
    const int bm = blockIdx.y * 128, bn = blockIdx.x * 128;

    // staging: wave w owns rows [w*32, w*32+32); two 16-row calls per tile.
    const int srow = wid * 32 + (lane >> 2);
    const int scol = (lane & 3) * 8;
    const unsigned short* Ag = A + (size_t)(bm + srow) * K + scol;
    const unsigned short* Bg = B + (size_t)(bn + srow) * K + scol;
    unsigned short* AsB = &As[(wid * 32) * 32];
    unsigned short* BsB = &Bs[(wid * 32) * 32];

    const int fr = lane & 15;   // fragment row/col
    const int fq = lane >> 4;   // k-quarter
    f32x4 acc[4][4] = {};

    for (int k0 = 0; k0 < K; k0 += 32) {
        gload_lds16(Ag + k0, AsB);
        gload_lds16(Ag + (size_t)16 * K + k0, AsB + 16 * 32);
        gload_lds16(Bg + k0, BsB);
        gload_lds16(Bg + (size_t)16 * K + k0, BsB + 16 * 32);
        __syncthreads();
        bf16x8 af[4], bf[4];
#pragma unroll
        for (int m = 0; m < 4; ++m)
            af[m] = *(const bf16x8*)&As[(wr * 64 + m * 16 + fr) * 32 + fq * 8];
#pragma unroll
        for (int n = 0; n < 4; ++n)
            bf[n] = *(const bf16x8*)&Bs[(wc * 64 + n * 16 + fr) * 32 + fq * 8];
#pragma unroll
        for (int m = 0; m < 4; ++m)
#pragma unroll
            for (int n = 0; n < 4; ++n)
                acc[m][n] = __builtin_amdgcn_mfma_f32_16x16x32_bf16(
                    af[m], bf[n], acc[m][n], 0, 0, 0);
        __syncthreads();
    }

#pragma unroll
    for (int m = 0; m < 4; ++m) {
#pragma unroll
        for (int n = 0; n < 4; ++n) {
            const int col = bn + wc * 64 + n * 16 + fr;
#pragma unroll
            for (int r = 0; r < 4; ++r) {
                const int row = bm + wr * 64 + m * 16 + fq * 4 + r;
                float o = acc[m][n][r];
                if (EPI == 2) o += X[(size_t)row * ldx + col];
                C[(size_t)row * ldc + col] = o;
            }
        }
    }
}

// ---------------------------------------------------------------------------
// fp32 NT GEMM (kept for the tiny dt projection, K=32).
// EPI 1: softplus(acc + 2*X[col])
// ---------------------------------------------------------------------------
template <int EPI>
__global__ __launch_bounds__(256) void gemm_nt(
    const float* __restrict__ A, int lda,
    const float* __restrict__ B, int ldb,
    float* __restrict__ C, int ldc,
    const float* __restrict__ X, int ldx,
    int M, int N, int K)
{
    __shared__ float As[16][68];
    __shared__ float Bs[16][68];
    const int bm = blockIdx.y * 64;
    const int bn = blockIdx.x * 64;
    const int tid = threadIdx.x;
    const int lm = tid >> 2;
    const int lk = (tid & 3) << 2;
    const int tn = (tid & 15) << 2;
    const int tm = (tid >> 4) << 2;

    float acc[4][4] = {};
    const float* Aptr = A + (size_t)(bm + lm) * lda + lk;
    const float* Bptr = B + (size_t)(bn + lm) * ldb + lk;

    for (int k0 = 0; k0 < K; k0 += 16) {
        const float4 av = *reinterpret_cast<const float4*>(Aptr + k0);
        const float4 bv = *reinterpret_cast<const float4*>(Bptr + k0);
        As[lk + 0][lm] = av.x; As[lk + 1][lm] = av.y;
        As[lk + 2][lm] = av.z; As[lk + 3][lm] = av.w;
        Bs[lk + 0][lm] = bv.x; Bs[lk + 1][lm] = bv.y;
        Bs[lk + 2][lm] = bv.z; Bs[lk + 3][lm] = bv.w;
        __syncthreads();
#pragma unroll
        for (int kk = 0; kk < 16; ++kk) {
            const float4 a = *reinterpret_cast<const float4*>(&As[kk][tm]);
            const float4 b = *reinterpret_cast<const float4*>(&Bs[kk][tn]);
            acc[0][0] += a.x * b.x; acc[0][1] += a.x * b.y; acc[0][2] += a.x * b.z; acc[0][3] += a.x * b.w;
            acc[1][0] += a.y * b.x; acc[1][1] += a.y * b.y; acc[1][2] += a.y * b.z; acc[1][3] += a.y * b.w;
            acc[2][0] += a.z * b.x; acc[2][1] += a.z * b.y; acc[2][2] += a.z * b.z; acc[2][3] += a.z * b.w;
            acc[3][0] += a.w * b.x; acc[3][1] += a.w * b.y; acc[3][2] += a.w * b.z; acc[3][3] += a.w * b.w;
        }
        __syncthreads();
    }

#pragma unroll
    for (int i = 0; i < 4; ++i) {
        const int row = bm + tm + i;
#pragma unroll
        for (int j = 0; j < 4; ++j) {
            const int col = bn + tn + j;
            float v = acc[i][j];
            if (EPI == 1) v = softplus_f(v + 2.0f * X[col]);
            if (EPI == 2) v += X[(size_t)row * ldx + col];
            C[(size_t)row * ldc + col] = v;
        }
    }
}

// ---------------------------------------------------------------------------
// Depthwise causal conv (k=4) + bias + SiLU.
// ---------------------------------------------------------------------------
__global__ __launch_bounds__(256) void conv_silu_kernel(
    const float* __restrict__ xz, const float* __restrict__ Wc,
    const float* __restrict__ bc, float* __restrict__ xcs)
{
    const int idx = blockIdx.x * 256 + threadIdx.x;
    if (idx >= BL * D_INNER) return;
    const int d = idx % D_INNER;
    const int bl = idx / D_INNER;
    const int l = bl % SEQ;
    const float w0 = Wc[d * 4 + 0], w1 = Wc[d * 4 + 1];
    const float w2 = Wc[d * 4 + 2], w3 = Wc[d * 4 + 3];
    float acc = bc[d] + w3 * xz[(size_t)bl * E2 + d];
    if (l >= 1) acc += w2 * xz[(size_t)(bl - 1) * E2 + d];
    if (l >= 2) acc += w1 * xz[(size_t)(bl - 2) * E2 + d];
    if (l >= 3) acc += w0 * xz[(size_t)(bl - 3) * E2 + d];
    xcs[idx] = silu_f(acc);
}

// ---------------------------------------------------------------------------
// x_dbl = xcs @ W_x^T   (M=2048, N=64, K=1536).
// ---------------------------------------------------------------------------
__global__ __launch_bounds__(256) void xdbl_kernel(
    const float* __restrict__ xcs, const float* __restrict__ W_x,
    float* __restrict__ xdbl)
{
    __shared__ float xr[8][1536];
    const int r0 = blockIdx.x * 8;
    const int tid = threadIdx.x;

    for (int v = tid; v < 8 * 1536 / 4; v += 256) {
        const int rr = v / 384;
        const int kk = (v % 384) * 4;
        *reinterpret_cast<float4*>(&xr[rr][kk]) =
            *reinterpret_cast<const float4*>(&xcs[(size_t)(r0 + rr) * D_INNER + kk]);
    }
    __syncthreads();

    const int j = tid & 63;
    const int rq = tid >> 6;
    const float* w = W_x + (size_t)j * D_INNER + rq * 384;
    float acc[8] = {};
    for (int k = 0; k < 384; k += 4) {
        const float4 wv = *reinterpret_cast<const float4*>(w + k);
#pragma unroll
        for (int r = 0; r < 8; ++r) {
            const float4 xv = *reinterpret_cast<const float4*>(&xr[r][rq * 384 + k]);
            acc[r] += wv.x * xv.x + wv.y * xv.y + wv.z * xv.z + wv.w * xv.w;
        }
    }
    __syncthreads();
    float* red = &xr[0][0];
#pragma unroll
    for (int r = 0; r < 8; ++r) red[j * 32 + rq * 8 + r] = acc[r];
    __syncthreads();
    if (rq == 0) {
#pragma unroll
        for (int r = 0; r < 8; ++r) {
            const float s = red[j * 32 + r] + red[j * 32 + 8 + r] +
                            red[j * 32 + 16 + r] + red[j * 32 + 24 + r];
            xdbl[(size_t)(r0 + r) * 64 + j] = s;
        }
    }
}

// ---------------------------------------------------------------------------
// Chunked selective scan (3 passes).
// ---------------------------------------------------------------------------
__global__ __launch_bounds__(256) void scan_pass1(
    const float* __restrict__ dtg, const float* __restrict__ xcs,
    const float* __restrict__ xdbl, const float* __restrict__ A_log,
    float* __restrict__ Ec, float* __restrict__ Hc)
{
    __shared__ float dt_s[TCH][16];
    __shared__ float xc_s[TCH][16];
    __shared__ float B_s[TCH][16];
    const int tid = threadIdx.x;
    const int s = tid & 15;
    const int dl = tid >> 4;
    const int d0 = blockIdx.x * 16;
    const int c = blockIdx.y;
    const int b = blockIdx.z;
    const int d = d0 + dl;
    const int r0 = b * SEQ + c * TCH;
    const float a = -__expf(A_log[d * D_STATE + s]);

#pragma unroll
    for (int p = 0; p < 4; ++p) {
        const int i = p * 16 + dl;
        const size_t r = (size_t)(r0 + i);
        dt_s[i][s] = dtg[r * D_INNER + d0 + s];
        xc_s[i][s] = xcs[r * D_INNER + d0 + s];
        B_s[i][s]  = xdbl[r * 64 + 32 + s];
    }
    __syncthreads();

    float E = 1.0f, h = 0.0f;
#pragma unroll 8
    for (int i = 0; i < TCH; ++i) {
        const float dtv = dt_s[i][dl];
        const float e = __expf(dtv * a);
        E *= e;
        h = e * h + dtv * B_s[i][s] * xc_s[i][dl];
    }
    const size_t o = ((size_t)(b * NCHUNK + c) * D_INNER + d) * 16 + s;
    Ec[o] = E;
    Hc[o] = h;
}

__global__ __launch_bounds__(256) void scan_pass2(
    const float* __restrict__ Ec, const float* __restrict__ Hc,
    float* __restrict__ Hinit)
{
    const int idx = blockIdx.x * 256 + threadIdx.x;
    if (idx >= BATCH * D_INNER * 16) return;
    const int b = idx / (D_INNER * 16);
    const int ds = idx % (D_INNER * 16);
    float h = 0.0f;
#pragma unroll
    for (int c = 0; c < NCHUNK; ++c) {
        const size_t o = (size_t)(b * NCHUNK + c) * (D_INNER * 16) + ds;
        Hinit[o] = h;
        h = Ec[o] * h + Hc[o];
    }
}

__global__ __launch_bounds__(256) void scan_pass3(
    const float* __restrict__ dtg, const float* __restrict__ xcs,
    const float* __restrict__ xdbl, const float* __restrict__ A_log,
    const float* __restrict__ Dp, const float* __restrict__ Hinit,
    float* __restrict__ y)   // y may alias dtg
{
    __shared__ float dt_s[TCH][16];
    __shared__ float xc_s[TCH][16];
    __shared__ float B_s[TCH][16];
    __shared__ float C_s[TCH][16];
    const int tid = threadIdx.x;
    const int s = tid & 15;
    const int dl = tid >> 4;
    const int d0 = blockIdx.x * 16;
    const int c = blockIdx.y;
    const int b = blockIdx.z;
    const int d = d0 + dl;
    const int r0 = b * SEQ + c * TCH;
    const float a = -__expf(A_log[d * D_STATE + s]);
    const float Dd = Dp[d];

#pragma unroll
    for (int p = 0; p < 4; ++p) {
        const int i = p * 16 + dl;
        const size_t r = (size_t)(r0 + i);
        dt_s[i][s] = dtg[r * D_INNER + d0 + s];
        xc_s[i][s] = xcs[r * D_INNER + d0 + s];
        B_s[i][s]  = xdbl[r * 64 + 32 + s];
        C_s[i][s]  = xdbl[r * 64 + 48 + s];
    }
    __syncthreads();

    float h = Hinit[((size_t)(b * NCHUNK + c) * D_INNER + d) * 16 + s];
#pragma unroll 4
    for (int i = 0; i < TCH; ++i) {
        const float dtv = dt_s[i][dl];
        const float xcv = xc_s[i][dl];
        const float e = __expf(dtv * a);
        h = e * h + dtv * B_s[i][s] * xcv;
        float v = h * C_s[i][s];
        v += __shfl_xor(v, 1);
        v += __shfl_xor(v, 2);
        v += __shfl_xor(v, 4);
        v += __shfl_xor(v, 8);
        if (s == 0) y[(size_t)(r0 + i) * D_INNER + d] = v + xcv * Dd;
    }
}

// ---------------------------------------------------------------------------
// ym = y * silu(z) -> bf16, 8 elems/thread.
// ---------------------------------------------------------------------------
__global__ __launch_bounds__(256) void ymul_bf16_kernel(
    const float* __restrict__ y, const float* __restrict__ xz,
    unsigned short* __restrict__ ymb)
{
    const int i = blockIdx.x * 256 + threadIdx.x;
    if (i >= BL * D_INNER / 8) return;
    const int row = i / (D_INNER / 8);
    const int c8 = i % (D_INNER / 8);
    const f32x4 y0 = ((const f32x4*)y)[2 * i];
    const f32x4 y1 = ((const f32x4*)y)[2 * i + 1];
    const float* zp = xz + (size_t)row * E2 + D_INNER + c8 * 8;
    const f32x4 z0 = *(const f32x4*)zp;
    const f32x4 z1 = *(const f32x4*)(zp + 4);
    u16x8 o;
#pragma unroll
    for (int j = 0; j < 4; ++j) {
        o[j]     = f2bf(y0[j] * silu_f(z0[j]));
        o[4 + j] = f2bf(y1[j] * silu_f(z1[j]));
    }
    ((u16x8*)ymb)[i] = o;
}

extern "C" void kernel_launch(void* const* d_in, const int* in_sizes, int n_in,
                              void* d_out, int out_size, void* d_ws, size_t ws_size,
                              hipStream_t stream) {
    const float* x      = (const float*)d_in[0];
    const float* W_in   = (const float*)d_in[1];
    const float* W_conv = (const float*)d_in[2];
    const float* b_conv = (const float*)d_in[3];
    const float* W_x    = (const float*)d_in[4];
    const float* W_dt   = (const float*)d_in[5];
    const float* b_dt   = (const float*)d_in[6];
    const float* A_log  = (const float*)d_in[7];
    const float* Dp     = (const float*)d_in[8];
    const float* W_out  = (const float*)d_in[9];
    float* out = (float*)d_out;

    float* ws    = (float*)d_ws;
    float* xz    = ws;                               // 6291456 f
    float* xcs   = xz + (size_t)BL * E2;             // 3145728 f
    float* xdbl  = xcs + (size_t)BL * D_INNER;       // 131072 f
    float* dtg   = xdbl + (size_t)BL * 64;           // 3145728 f (also y)
    float* shr   = dtg + (size_t)BL * D_INNER;       // shared region, 2359296 f
    // phase A (pre-GEMM1):
    unsigned short* W_in_b = (unsigned short*)shr;                  // 2359296 us
    unsigned short* xb     = (unsigned short*)(shr + 1179648);      // 1572864 us
    // phase S (scan):
    float* Ec    = shr;
    float* Hc    = shr + 786432;
    float* Hinit = shr + 1572864;
    // phase B (post-scan):
    unsigned short* ymb     = (unsigned short*)shr;                 // 3145728 us
    unsigned short* W_out_b = (unsigned short*)(shr + 1572864);     // 1179648 us
    float* yb = dtg;

    // 0. bf16 conversions for GEMM1
    cvt_bf16_kernel<<<(E2 * DIM / 8) / 256, 256, 0, stream>>>(W_in, W_in_b, E2 * DIM / 8);
    cvt_bf16_kernel<<<(BL * DIM / 8) / 256, 256, 0, stream>>>(x, xb, BL * DIM / 8);
    // 1. xz = x @ W_in^T  (bf16 MFMA)
    gemm_bf16<0><<<dim3(E2 / 128, BL / 128), 256, 0, stream>>>(
        xb, W_in_b, xz, E2, nullptr, 0, DIM);
    // 2. depthwise causal conv + bias + silu
    conv_silu_kernel<<<(BL * D_INNER) / 256, 256, 0, stream>>>(xz, W_conv, b_conv, xcs);
    // 3. x_dbl = xcs @ W_x^T
    xdbl_kernel<<<BL / 8, 256, 0, stream>>>(xcs, W_x, xdbl);
    // 4. dt = softplus(dt_lr @ W_dt^T + 2*b_dt)
    gemm_nt<1><<<dim3(D_INNER / 64, BL / 64), 256, 0, stream>>>(
        xdbl, 64, W_dt, DT_RANK, dtg, D_INNER, b_dt, 0, BL, D_INNER, DT_RANK);
    // 5. chunked selective scan -> y (over dtg)
    scan_pass1<<<dim3(D_INNER / 16, NCHUNK, BATCH), 256, 0, stream>>>(
        dtg, xcs, xdbl, A_log, Ec, Hc);
    scan_pass2<<<(BATCH * D_INNER * 16) / 256, 256, 0, stream>>>(Ec, Hc, Hinit);
    scan_pass3<<<dim3(D_INNER / 16, NCHUNK, BATCH), 256, 0, stream>>>(
        dtg, xcs, xdbl, A_log, Dp, Hinit, yb);
    // 6. ym = y * silu(z) -> bf16;  W_out -> bf16
    ymul_bf16_kernel<<<(BL * D_INNER / 8) / 256, 256, 0, stream>>>(yb, xz, ymb);
    cvt_bf16_kernel<<<(DIM * D_INNER / 8) / 256, 256, 0, stream>>>(W_out, W_out_b, DIM * D_INNER / 8);
    // 7. out = ym @ W_out^T + x  (bf16 MFMA)
    gemm_bf16<2><<<dim3(DIM / 128, BL / 128), 256, 0, stream>>>(
        ymb, W_out_b, out, DIM, x, DIM, D_INNER);
}

// Round 4
// 176.519 us; speedup vs baseline: 2.8136x; 1.1609x over previous
//
#include <hip/hip_runtime.h>
#include <stdint.h>

#define DIM 768
#define D_STATE 16
#define D_CONV 4
#define DT_RANK 32
#define D_INNER 1536
#define BATCH 2
#define SEQ 1024
#define BL (BATCH * SEQ)   // 2048
#define E2 (2 * D_INNER)   // 3072
#define NCHUNK 64
#define TC (SEQ / NCHUNK)  // 16 steps per chunk

typedef __attribute__((ext_vector_type(8))) __bf16 bf16x8;
typedef __attribute__((ext_vector_type(4))) float f32x4;
typedef __attribute__((ext_vector_type(8))) unsigned short u16x8;

__device__ __forceinline__ float silu_f(float v) {
    return v / (1.0f + __expf(-v));
}
__device__ __forceinline__ float softplus_f(float v) {
    return fmaxf(v, 0.0f) + log1pf(__expf(-fabsf(v)));
}
__device__ __forceinline__ unsigned short f2bf(float f) {
    uint32_t u = __float_as_uint(f);
    u += 0x7FFFu + ((u >> 16) & 1u);          // round-to-nearest-even
    return (unsigned short)(u >> 16);
}
// global -> LDS direct copy, 16B per lane. LDS dest: wave-uniform base + lane*16.
__device__ __forceinline__ void gload_lds16(const void* g, void* l) {
    __builtin_amdgcn_global_load_lds(
        (const __attribute__((address_space(1))) unsigned int*)(uintptr_t)g,
        (__attribute__((address_space(3))) unsigned int*)(uint32_t)(uintptr_t)l,
        16, 0, 0);
}

// ---------------------------------------------------------------------------
// f32 -> bf16 conversion, 8 elems/thread.
// ---------------------------------------------------------------------------
__global__ __launch_bounds__(256) void cvt_bf16_kernel(
    const float* __restrict__ src, unsigned short* __restrict__ dst, int n8)
{
    const int i = blockIdx.x * 256 + threadIdx.x;
    if (i >= n8) return;
    const f32x4 a = ((const f32x4*)src)[2 * i];
    const f32x4 b = ((const f32x4*)src)[2 * i + 1];
    u16x8 o;
#pragma unroll
    for (int j = 0; j < 4; ++j) { o[j] = f2bf(a[j]); o[4 + j] = f2bf(b[j]); }
    ((u16x8*)dst)[i] = o;
}

// ---------------------------------------------------------------------------
// bf16 MFMA GEMM: C[M,N] fp32 = A[M,K]bf16 * B[N,K]^T bf16 (+X residual).
// 128x128 tile, BK=32, 4 waves (2x2), 16x16x32 MFMA, 4x4 frags/wave.
// ---------------------------------------------------------------------------
template <int EPI>
__global__ __launch_bounds__(256) void gemm_bf16(
    const unsigned short* __restrict__ A, const unsigned short* __restrict__ B,
    float* __restrict__ C, int ldc,
    const float* __restrict__ X, int ldx, int K)
{
    __shared__ __align__(16) unsigned short As[128 * 32];
    __shared__ __align__(16) unsigned short Bs[128 * 32];
    const int tid = threadIdx.x;
    const int wid = tid >> 6;
    const int lane = tid & 63;
    const int wr = wid >> 1, wc = wid & 1;
    const int bm = blockIdx.y * 128, bn = blockIdx.x * 128;

    const int srow = wid * 32 + (lane >> 2);
    const int scol = (lane & 3) * 8;
    const unsigned short* Ag = A + (size_t)(bm + srow) * K + scol;
    const unsigned short* Bg = B + (size_t)(bn + srow) * K + scol;
    unsigned short* AsB = &As[(wid * 32) * 32];
    unsigned short* BsB = &Bs[(wid * 32) * 32];

    const int fr = lane & 15;
    const int fq = lane >> 4;
    f32x4 acc[4][4] = {};

    for (int k0 = 0; k0 < K; k0 += 32) {
        gload_lds16(Ag + k0, AsB);
        gload_lds16(Ag + (size_t)16 * K + k0, AsB + 16 * 32);
        gload_lds16(Bg + k0, BsB);
        gload_lds16(Bg + (size_t)16 * K + k0, BsB + 16 * 32);
        __syncthreads();
        bf16x8 af[4], bf[4];
#pragma unroll
        for (int m = 0; m < 4; ++m)
            af[m] = *(const bf16x8*)&As[(wr * 64 + m * 16 + fr) * 32 + fq * 8];
#pragma unroll
        for (int n = 0; n < 4; ++n)
            bf[n] = *(const bf16x8*)&Bs[(wc * 64 + n * 16 + fr) * 32 + fq * 8];
#pragma unroll
        for (int m = 0; m < 4; ++m)
#pragma unroll
            for (int n = 0; n < 4; ++n)
                acc[m][n] = __builtin_amdgcn_mfma_f32_16x16x32_bf16(
                    af[m], bf[n], acc[m][n], 0, 0, 0);
        __syncthreads();
    }

#pragma unroll
    for (int m = 0; m < 4; ++m) {
#pragma unroll
        for (int n = 0; n < 4; ++n) {
            const int col = bn + wc * 64 + n * 16 + fr;
#pragma unroll
            for (int r = 0; r < 4; ++r) {
                const int row = bm + wr * 64 + m * 16 + fq * 4 + r;
                float o = acc[m][n][r];
                if (EPI == 2) o += X[(size_t)row * ldx + col];
                C[(size_t)row * ldc + col] = o;
            }
        }
    }
}

// ---------------------------------------------------------------------------
// fp32 NT GEMM (tiny dt projection, K=32).  EPI 1: softplus(acc + 2*X[col])
// ---------------------------------------------------------------------------
template <int EPI>
__global__ __launch_bounds__(256) void gemm_nt(
    const float* __restrict__ A, int lda,
    const float* __restrict__ B, int ldb,
    float* __restrict__ C, int ldc,
    const float* __restrict__ X, int ldx,
    int M, int N, int K)
{
    __shared__ float As[16][68];
    __shared__ float Bs[16][68];
    const int bm = blockIdx.y * 64;
    const int bn = blockIdx.x * 64;
    const int tid = threadIdx.x;
    const int lm = tid >> 2;
    const int lk = (tid & 3) << 2;
    const int tn = (tid & 15) << 2;
    const int tm = (tid >> 4) << 2;

    float acc[4][4] = {};
    const float* Aptr = A + (size_t)(bm + lm) * lda + lk;
    const float* Bptr = B + (size_t)(bn + lm) * ldb + lk;

    for (int k0 = 0; k0 < K; k0 += 16) {
        const float4 av = *reinterpret_cast<const float4*>(Aptr + k0);
        const float4 bv = *reinterpret_cast<const float4*>(Bptr + k0);
        As[lk + 0][lm] = av.x; As[lk + 1][lm] = av.y;
        As[lk + 2][lm] = av.z; As[lk + 3][lm] = av.w;
        Bs[lk + 0][lm] = bv.x; Bs[lk + 1][lm] = bv.y;
        Bs[lk + 2][lm] = bv.z; Bs[lk + 3][lm] = bv.w;
        __syncthreads();
#pragma unroll
        for (int kk = 0; kk < 16; ++kk) {
            const float4 a = *reinterpret_cast<const float4*>(&As[kk][tm]);
            const float4 b = *reinterpret_cast<const float4*>(&Bs[kk][tn]);
            acc[0][0] += a.x * b.x; acc[0][1] += a.x * b.y; acc[0][2] += a.x * b.z; acc[0][3] += a.x * b.w;
            acc[1][0] += a.y * b.x; acc[1][1] += a.y * b.y; acc[1][2] += a.y * b.z; acc[1][3] += a.y * b.w;
            acc[2][0] += a.z * b.x; acc[2][1] += a.z * b.y; acc[2][2] += a.z * b.z; acc[2][3] += a.z * b.w;
            acc[3][0] += a.w * b.x; acc[3][1] += a.w * b.y; acc[3][2] += a.w * b.z; acc[3][3] += a.w * b.w;
        }
        __syncthreads();
    }

#pragma unroll
    for (int i = 0; i < 4; ++i) {
        const int row = bm + tm + i;
#pragma unroll
        for (int j = 0; j < 4; ++j) {
            const int col = bn + tn + j;
            float v = acc[i][j];
            if (EPI == 1) v = softplus_f(v + 2.0f * X[col]);
            if (EPI == 2) v += X[(size_t)row * ldx + col];
            C[(size_t)row * ldc + col] = v;
        }
    }
}

// ---------------------------------------------------------------------------
// Depthwise causal conv (k=4) + bias + SiLU.
// ---------------------------------------------------------------------------
__global__ __launch_bounds__(256) void conv_silu_kernel(
    const float* __restrict__ xz, const float* __restrict__ Wc,
    const float* __restrict__ bc, float* __restrict__ xcs)
{
    const int idx = blockIdx.x * 256 + threadIdx.x;
    if (idx >= BL * D_INNER) return;
    const int d = idx % D_INNER;
    const int bl = idx / D_INNER;
    const int l = bl % SEQ;
    const float w0 = Wc[d * 4 + 0], w1 = Wc[d * 4 + 1];
    const float w2 = Wc[d * 4 + 2], w3 = Wc[d * 4 + 3];
    float acc = bc[d] + w3 * xz[(size_t)bl * E2 + d];
    if (l >= 1) acc += w2 * xz[(size_t)(bl - 1) * E2 + d];
    if (l >= 2) acc += w1 * xz[(size_t)(bl - 2) * E2 + d];
    if (l >= 3) acc += w0 * xz[(size_t)(bl - 3) * E2 + d];
    xcs[idx] = silu_f(acc);
}

// ---------------------------------------------------------------------------
// x_dbl = xcs @ W_x^T   (M=2048, N=64, K=1536).
// ---------------------------------------------------------------------------
__global__ __launch_bounds__(256) void xdbl_kernel(
    const float* __restrict__ xcs, const float* __restrict__ W_x,
    float* __restrict__ xdbl)
{
    __shared__ float xr[8][1536];
    const int r0 = blockIdx.x * 8;
    const int tid = threadIdx.x;

    for (int v = tid; v < 8 * 1536 / 4; v += 256) {
        const int rr = v / 384;
        const int kk = (v % 384) * 4;
        *reinterpret_cast<float4*>(&xr[rr][kk]) =
            *reinterpret_cast<const float4*>(&xcs[(size_t)(r0 + rr) * D_INNER + kk]);
    }
    __syncthreads();

    const int j = tid & 63;
    const int rq = tid >> 6;
    const float* w = W_x + (size_t)j * D_INNER + rq * 384;
    float acc[8] = {};
    for (int k = 0; k < 384; k += 4) {
        const float4 wv = *reinterpret_cast<const float4*>(w + k);
#pragma unroll
        for (int r = 0; r < 8; ++r) {
            const float4 xv = *reinterpret_cast<const float4*>(&xr[r][rq * 384 + k]);
            acc[r] += wv.x * xv.x + wv.y * xv.y + wv.z * xv.z + wv.w * xv.w;
        }
    }
    __syncthreads();
    float* red = &xr[0][0];
#pragma unroll
    for (int r = 0; r < 8; ++r) red[j * 32 + rq * 8 + r] = acc[r];
    __syncthreads();
    if (rq == 0) {
#pragma unroll
        for (int r = 0; r < 8; ++r) {
            const float s = red[j * 32 + r] + red[j * 32 + 8 + r] +
                            red[j * 32 + 16 + r] + red[j * 32 + 24 + r];
            xdbl[(size_t)(r0 + r) * 64 + j] = s;
        }
    }
}

// ---------------------------------------------------------------------------
// Chunked selective scan, thread-per-channel (16 states in registers).
// Pass1: local scan from h=0 over TC=16 steps; store h[16] and sum(dt).
// Pass2: sequential chunk combine, E recomputed as exp(a*sum_dt); Hinit in
//        place over Hc.  Pass3: rescan from Hinit, fused y*silu(z)->bf16.
// Grid pass1/3: (D_INNER/256, NCHUNK, BATCH) = (6,64,2); no shuffles.
// ---------------------------------------------------------------------------
__global__ __launch_bounds__(256) void scan_p1(
    const float* __restrict__ dtg, const float* __restrict__ xcs,
    const float* __restrict__ xdbl, const float* __restrict__ A_log,
    float* __restrict__ Hc, float* __restrict__ sdt_arr)
{
    __shared__ float Bsh[TC][16];
    const int tid = threadIdx.x;
    const int d = blockIdx.x * 256 + tid;
    const int c = blockIdx.y;
    const int b = blockIdx.z;
    const int r0 = b * SEQ + c * TC;
    {
        const int t = tid >> 4, j = tid & 15;   // 256 = 16*16 exact
        Bsh[t][j] = xdbl[(size_t)(r0 + t) * 64 + 32 + j];
    }
    float a[16];
#pragma unroll
    for (int q = 0; q < 4; ++q) {
        const f32x4 al = *(const f32x4*)&A_log[(size_t)d * 16 + q * 4];
#pragma unroll
        for (int j = 0; j < 4; ++j) a[q * 4 + j] = -__expf(al[j]);
    }
    __syncthreads();

    float h[16];
#pragma unroll
    for (int s = 0; s < 16; ++s) h[s] = 0.0f;
    float sdt = 0.0f;
    const size_t base = (size_t)r0 * D_INNER + d;
    float dt = dtg[base], xc = xcs[base];
    for (int t = 0; t < TC; ++t) {
        const size_t nb = base + (size_t)(t + 1 < TC ? t + 1 : t) * D_INNER;
        const float dtn = dtg[nb], xcn = xcs[nb];
        sdt += dt;
        const float u = dt * xc;
        const f32x4 B0 = *(const f32x4*)&Bsh[t][0];
        const f32x4 B1 = *(const f32x4*)&Bsh[t][4];
        const f32x4 B2 = *(const f32x4*)&Bsh[t][8];
        const f32x4 B3 = *(const f32x4*)&Bsh[t][12];
#pragma unroll
        for (int s = 0; s < 16; ++s) {
            const float Bv = (s < 4 ? B0[s] : s < 8 ? B1[s - 4] : s < 12 ? B2[s - 8] : B3[s - 12]);
            h[s] = __expf(dt * a[s]) * h[s] + u * Bv;
        }
        dt = dtn; xc = xcn;
    }
    const size_t o = (((size_t)b * NCHUNK + c) * D_INNER + d) * 16;
#pragma unroll
    for (int q = 0; q < 4; ++q) {
        f32x4 hv; hv[0] = h[q*4]; hv[1] = h[q*4+1]; hv[2] = h[q*4+2]; hv[3] = h[q*4+3];
        *(f32x4*)&Hc[o + q * 4] = hv;
    }
    sdt_arr[((size_t)b * NCHUNK + c) * D_INNER + d] = sdt;
}

__global__ __launch_bounds__(256) void scan_p2(
    float* __restrict__ Hc, const float* __restrict__ sdt_arr,
    const float* __restrict__ A_log)
{
    const int idx = blockIdx.x * 256 + threadIdx.x;   // b*(D_INNER*16) + d*16 + s
    if (idx >= BATCH * D_INNER * 16) return;
    const int b = idx / (D_INNER * 16);
    const int ds = idx % (D_INNER * 16);
    const int d = ds >> 4;
    const float a = -__expf(A_log[ds]);
    float h = 0.0f;
    for (int c = 0; c < NCHUNK; ++c) {
        const size_t o = ((size_t)b * NCHUNK + c) * (D_INNER * 16) + ds;
        const float hc = Hc[o];
        const float E = __expf(sdt_arr[((size_t)b * NCHUNK + c) * D_INNER + d] * a);
        Hc[o] = h;                 // becomes Hinit
        h = E * h + hc;
    }
}

__global__ __launch_bounds__(256) void scan_p3(
    const float* __restrict__ dtg, const float* __restrict__ xcs,
    const float* __restrict__ xdbl, const float* __restrict__ A_log,
    const float* __restrict__ Dp, const float* __restrict__ Hinit,
    const float* __restrict__ xz, unsigned short* __restrict__ ymb)
{
    __shared__ float BCsh[TC][32];   // [t][0..15]=B, [t][16..31]=C
    const int tid = threadIdx.x;
    const int d = blockIdx.x * 256 + tid;
    const int c = blockIdx.y;
    const int b = blockIdx.z;
    const int r0 = b * SEQ + c * TC;
    for (int i = tid; i < TC * 32; i += 256) {
        const int t = i >> 5, j = i & 31;
        BCsh[t][j] = xdbl[(size_t)(r0 + t) * 64 + 32 + j];
    }
    float a[16];
#pragma unroll
    for (int q = 0; q < 4; ++q) {
        const f32x4 al = *(const f32x4*)&A_log[(size_t)d * 16 + q * 4];
#pragma unroll
        for (int j = 0; j < 4; ++j) a[q * 4 + j] = -__expf(al[j]);
    }
    const float Dd = Dp[d];
    float h[16];
    {
        const size_t o = (((size_t)b * NCHUNK + c) * D_INNER + d) * 16;
#pragma unroll
        for (int q = 0; q < 4; ++q) {
            const f32x4 hv = *(const f32x4*)&Hinit[o + q * 4];
#pragma unroll
            for (int j = 0; j < 4; ++j) h[q * 4 + j] = hv[j];
        }
    }
    __syncthreads();

    const size_t base = (size_t)r0 * D_INNER + d;
    const size_t zbase = (size_t)r0 * E2 + D_INNER + d;
    float dt = dtg[base], xc = xcs[base], z = xz[zbase];
    for (int t = 0; t < TC; ++t) {
        const int tn = (t + 1 < TC ? t + 1 : t);
        const float dtn = dtg[base + (size_t)tn * D_INNER];
        const float xcn = xcs[base + (size_t)tn * D_INNER];
        const float zn  = xz[zbase + (size_t)tn * E2];
        const float u = dt * xc;
        const f32x4 B0 = *(const f32x4*)&BCsh[t][0];
        const f32x4 B1 = *(const f32x4*)&BCsh[t][4];
        const f32x4 B2 = *(const f32x4*)&BCsh[t][8];
        const f32x4 B3 = *(const f32x4*)&BCsh[t][12];
        const f32x4 C0 = *(const f32x4*)&BCsh[t][16];
        const f32x4 C1 = *(const f32x4*)&BCsh[t][20];
        const f32x4 C2 = *(const f32x4*)&BCsh[t][24];
        const f32x4 C3 = *(const f32x4*)&BCsh[t][28];
        float y = 0.0f;
#pragma unroll
        for (int s = 0; s < 16; ++s) {
            const float Bv = (s < 4 ? B0[s] : s < 8 ? B1[s - 4] : s < 12 ? B2[s - 8] : B3[s - 12]);
            const float Cv = (s < 4 ? C0[s] : s < 8 ? C1[s - 4] : s < 12 ? C2[s - 8] : C3[s - 12]);
            h[s] = __expf(dt * a[s]) * h[s] + u * Bv;
            y += h[s] * Cv;
        }
        y += xc * Dd;
        ymb[base + (size_t)t * D_INNER] = f2bf(y * silu_f(z));
        dt = dtn; xc = xcn; z = zn;
    }
}

extern "C" void kernel_launch(void* const* d_in, const int* in_sizes, int n_in,
                              void* d_out, int out_size, void* d_ws, size_t ws_size,
                              hipStream_t stream) {
    const float* x      = (const float*)d_in[0];
    const float* W_in   = (const float*)d_in[1];
    const float* W_conv = (const float*)d_in[2];
    const float* b_conv = (const float*)d_in[3];
    const float* W_x    = (const float*)d_in[4];
    const float* W_dt   = (const float*)d_in[5];
    const float* b_dt   = (const float*)d_in[6];
    const float* A_log  = (const float*)d_in[7];
    const float* Dp     = (const float*)d_in[8];
    const float* W_out  = (const float*)d_in[9];
    float* out = (float*)d_out;

    float* ws    = (float*)d_ws;
    float* xz    = ws;                               // 6291456 f
    float* xcs   = xz + (size_t)BL * E2;             // 3145728 f
    float* xdbl  = xcs + (size_t)BL * D_INNER;       // 131072 f
    float* dtg   = xdbl + (size_t)BL * 64;           // 3145728 f
    float* shr   = dtg + (size_t)BL * D_INNER;       // shared region
    // phase A (pre-GEMM1):
    unsigned short* W_in_b = (unsigned short*)shr;                  // 1179648 f
    unsigned short* xb     = (unsigned short*)(shr + 1179648);      // 786432 f
    // phase S (scan) / phase B (output):
    float* Hc   = shr;                               // 3145728 f (then Hinit)
    float* sdt  = shr + 3145728;                     // 196608 f
    unsigned short* ymb     = (unsigned short*)(shr + 3342336);     // 1572864 f
    unsigned short* W_out_b = (unsigned short*)(shr + 4915200);     // 589824 f

    // 0. bf16 conversions for GEMM1
    cvt_bf16_kernel<<<(E2 * DIM / 8) / 256, 256, 0, stream>>>(W_in, W_in_b, E2 * DIM / 8);
    cvt_bf16_kernel<<<(BL * DIM / 8) / 256, 256, 0, stream>>>(x, xb, BL * DIM / 8);
    // 1. xz = x @ W_in^T  (bf16 MFMA)
    gemm_bf16<0><<<dim3(E2 / 128, BL / 128), 256, 0, stream>>>(
        xb, W_in_b, xz, E2, nullptr, 0, DIM);
    // 2. depthwise causal conv + bias + silu
    conv_silu_kernel<<<(BL * D_INNER) / 256, 256, 0, stream>>>(xz, W_conv, b_conv, xcs);
    // 3. x_dbl = xcs @ W_x^T
    xdbl_kernel<<<BL / 8, 256, 0, stream>>>(xcs, W_x, xdbl);
    // 4. dt = softplus(dt_lr @ W_dt^T + 2*b_dt)
    gemm_nt<1><<<dim3(D_INNER / 64, BL / 64), 256, 0, stream>>>(
        xdbl, 64, W_dt, DT_RANK, dtg, D_INNER, b_dt, 0, BL, D_INNER, DT_RANK);
    // 5. chunked selective scan (thread-per-channel), pass3 fuses y*silu(z)->bf16
    scan_p1<<<dim3(D_INNER / 256, NCHUNK, BATCH), 256, 0, stream>>>(
        dtg, xcs, xdbl, A_log, Hc, sdt);
    scan_p2<<<(BATCH * D_INNER * 16) / 256, 256, 0, stream>>>(Hc, sdt, A_log);
    scan_p3<<<dim3(D_INNER / 256, NCHUNK, BATCH), 256, 0, stream>>>(
        dtg, xcs, xdbl, A_log, Dp, Hc, xz, ymb);
    // 6. W_out -> bf16
    cvt_bf16_kernel<<<(DIM * D_INNER / 8) / 256, 256, 0, stream>>>(W_out, W_out_b, DIM * D_INNER / 8);
    // 7. out = ym @ W_out^T + x  (bf16 MFMA)
    gemm_bf16<2><<<dim3(DIM / 128, BL / 128), 256, 0, stream>>>(
        ymb, W_out_b, out, DIM, x, DIM, D_INNER);
}